// Round 7
// baseline (80.236 us; speedup 1.0000x reference)
//
#include <hip/hip_runtime.h>
#include <hip/hip_bf16.h>

// QLoRA SwiGLU MLP, B=16 tokens, d=4096, h=11008, r=2.
// tile(wq,(1,4)) => x @ W^T == fold4(x) @ wq^T  (skinny GEMM, K = in/4).
// R7: (1) sched_barrier(0) pins next-column weight loads BEFORE current
//     compute (R1/R6 showed VGPR=88 -> compiler sank the prefetch);
//     (2) gateup grid 512 blocks = 2 blocks/CU = 16 waves/CU.
// VGPR discipline: peak live ~120 < 128 cap for 512-thr blocks.

#define NB     16
#define DMODEL 4096
#define HID    11008
#define DQ     1024   // DMODEL/4
#define HQ     2752   // HID/4

// workspace layout (float offsets)
#define XS1_OFF 0         // xs f32 [16][1024]
#define T1_OFF  16384     // [16][2] f32
#define T3_OFF  16416
#define HVT_OFF 16448     // hvecT f32 [11008][16]
#define HSB_OFF 192576    // hs bf16 [16][2752] = 22016 floats
#define T2_OFF  214592    // [16][2] f32

__device__ __forceinline__ unsigned short f2bf(float f) {
  unsigned u = __float_as_uint(f);
  unsigned r = u + 0x7fffu + ((u >> 16) & 1u);   // RNE
  return (unsigned short)(r >> 16);
}

// ---------------------------------------------------------------------------
// prep1: xs[b][j] = sum_k x[b][k*1024+j] (f32); t1,t3 = LoRA A dots.
__global__ __launch_bounds__(256) void k_prep1(const float* __restrict__ x,
                                               const float* __restrict__ a1,
                                               const float* __restrict__ a3,
                                               float* __restrict__ ws) {
  const int b = blockIdx.x, t = threadIdx.x;
  const float4* x4  = (const float4*)(x) + b * (DMODEL / 4);
  const float4* a14 = (const float4*)a1;
  const float4* a34 = (const float4*)a3;
  float4 xs = make_float4(0.f, 0.f, 0.f, 0.f);
  float s10 = 0.f, s11 = 0.f, s30 = 0.f, s31 = 0.f;
#pragma unroll
  for (int k = 0; k < 4; ++k) {
    float4 xv  = x4[k * 256 + t];
    xs.x += xv.x; xs.y += xv.y; xs.z += xv.z; xs.w += xv.w;
    float4 a10 = a14[k * 256 + t];
    float4 a11 = a14[1024 + k * 256 + t];
    float4 a30 = a34[k * 256 + t];
    float4 a31 = a34[1024 + k * 256 + t];
    s10 += xv.x * a10.x + xv.y * a10.y + xv.z * a10.z + xv.w * a10.w;
    s11 += xv.x * a11.x + xv.y * a11.y + xv.z * a11.z + xv.w * a11.w;
    s30 += xv.x * a30.x + xv.y * a30.y + xv.z * a30.z + xv.w * a30.w;
    s31 += xv.x * a31.x + xv.y * a31.y + xv.z * a31.z + xv.w * a31.w;
  }
  ((float4*)(ws + XS1_OFF))[b * 256 + t] = xs;

  __shared__ float4 rb[256];
  rb[t] = make_float4(s10, s11, s30, s31);
  __syncthreads();
  for (int s = 128; s > 0; s >>= 1) {
    if (t < s) {
      rb[t].x += rb[t + s].x; rb[t].y += rb[t + s].y;
      rb[t].z += rb[t + s].z; rb[t].w += rb[t + s].w;
    }
    __syncthreads();
  }
  if (t == 0) {
    ws[T1_OFF + b * 2]     = rb[0].x;
    ws[T1_OFF + b * 2 + 1] = rb[0].y;
    ws[T3_OFF + b * 2]     = rb[0].z;
    ws[T3_OFF + b * 2 + 1] = rb[0].w;
  }
}

// ---------------------------------------------------------------------------
// gateup: 512 blocks x 512 thr (2 blocks/CU); xs f32 staged once in 64KB LDS.
// Cols per wave: base, base+4096, base+8192(if <HID). Weight loads for the
// next column are pinned before the current compute via sched_barrier(0).
#define GU_LOADW(OCOL, W1, W3) do {                                         \
    const float4* _p1 = (const float4*)w1q + (size_t)(OCOL) * 256;          \
    const float4* _p3 = (const float4*)w3q + (size_t)(OCOL) * 256;          \
    _Pragma("unroll")                                                       \
    for (int c = 0; c < 4; ++c) {                                           \
      W1[c] = _p1[c * 64 + lane];                                           \
      W3[c] = _p3[c * 64 + lane];                                           \
    }                                                                       \
  } while (0)

#define GU_COMPUTE(OCOL, W1, W3) do {                                       \
    float V[32];                                                            \
    _Pragma("unroll") for (int i = 0; i < 32; ++i) V[i] = 0.f;              \
    _Pragma("unroll")                                                       \
    for (int c = 0; c < 4; ++c) {                                           \
      const int idx = c * 64 + lane;                                        \
      const float4 w1v = W1[c], w3v = W3[c];                                \
      _Pragma("unroll")                                                     \
      for (int b = 0; b < 16; ++b) {                                        \
        const float4 xv = ldsf[b * 256 + idx];                              \
        V[2 * b]     += w1v.x * xv.x + w1v.y * xv.y + w1v.z * xv.z + w1v.w * xv.w; \
        V[2 * b + 1] += w3v.x * xv.x + w3v.y * xv.y + w3v.z * xv.z + w3v.w * xv.w; \
      }                                                                     \
    }                                                                       \
    _Pragma("unroll")                                                       \
    for (int s = 0; s < 4; ++s) {                                           \
      const int off = 1 << s, n2 = 16 >> s;                                 \
      _Pragma("unroll")                                                     \
      for (int i = 0; i < n2; ++i) {                                        \
        float lo = V[i], hi = V[i + n2];                                    \
        float send = (lane & off) ? lo : hi;                                \
        float got = __shfl_xor(send, off);                                  \
        V[i] = (lane & off) ? (hi + got) : (lo + got);                      \
      }                                                                     \
    }                                                                       \
    V[0] += __shfl_xor(V[0], 16); V[0] += __shfl_xor(V[0], 32);             \
    V[1] += __shfl_xor(V[1], 16); V[1] += __shfl_xor(V[1], 32);             \
    if (lane < 16) {                                                        \
      const int b = ((lane & 1) << 3) | ((lane & 2) << 1) |                 \
                    ((lane & 4) >> 1) | ((lane & 8) >> 3);                  \
      const float g = V[0] + 0.5f * (ws[T1_OFF + 2 * b] * b1[2 * (OCOL)] +  \
                                     ws[T1_OFF + 2 * b + 1] * b1[2 * (OCOL) + 1]); \
      const float u = V[1] + 0.5f * (ws[T3_OFF + 2 * b] * b3[2 * (OCOL)] +  \
                                     ws[T3_OFF + 2 * b + 1] * b3[2 * (OCOL) + 1]); \
      hvecT[(OCOL) * 16 + b] = (g / (1.f + __expf(-g))) * u;                \
    }                                                                       \
  } while (0)

__global__ __launch_bounds__(512) void k_gateup(const float* __restrict__ w1q,
                                                const float* __restrict__ w3q,
                                                const float* __restrict__ b1,
                                                const float* __restrict__ b3,
                                                const float* __restrict__ ws,
                                                float* __restrict__ hvecT) {
  __shared__ float4 lds4[4096];   // xs f32 [16][1024] = 64 KB
  const int t = threadIdx.x;
  const int wave = t >> 6, lane = t & 63;
  const int base = blockIdx.x * 8 + wave;       // 0..4095

  float4 A1[4], A3[4], B1[4], B3[4];
  GU_LOADW(base, A1, A3);          // col-0 weights in flight during staging

  const float4* xs4 = (const float4*)(ws + XS1_OFF);
#pragma unroll
  for (int i = 0; i < 8; ++i) lds4[t + i * 512] = xs4[t + i * 512];
  __syncthreads();

  const float4* ldsf = lds4;
  GU_LOADW(base + 4096, B1, B3);                // always valid (max 8191)
  __builtin_amdgcn_sched_barrier(0);            // pin: loads issued before compute
  GU_COMPUTE(base, A1, A3);

  const int o2 = base + 8192;                   // valid iff base < 2816
  const bool v2 = (o2 < HID);
  GU_LOADW(v2 ? o2 : base, A1, A3);
  __builtin_amdgcn_sched_barrier(0);
  GU_COMPUTE(base + 4096, B1, B3);
  if (v2) GU_COMPUTE(o2, A1, A3);
}

// ---------------------------------------------------------------------------
// prep2: hs[b][j] = sum_k hvec[b][k*2752+j] (stored bf16); t2 = hvec·a2^T.
__global__ __launch_bounds__(256) void k_prep2(const float* __restrict__ hvecT,
                                               const float* __restrict__ a2,
                                               float* __restrict__ ws) {
  const int b = blockIdx.x, t = threadIdx.x;
  float s0 = 0.f, s1 = 0.f;
  unsigned short* hsb = (unsigned short*)(ws + HSB_OFF);
  for (int j = t; j < HQ; j += 256) {
    float v0 = hvecT[j * 16 + b];
    float v1 = hvecT[(j + HQ) * 16 + b];
    float v2 = hvecT[(j + 2 * HQ) * 16 + b];
    float v3 = hvecT[(j + 3 * HQ) * 16 + b];
    hsb[b * HQ + j] = f2bf(v0 + v1 + v2 + v3);
    s0 += v0 * a2[j] + v1 * a2[j + HQ] + v2 * a2[j + 2 * HQ] + v3 * a2[j + 3 * HQ];
    s1 += v0 * a2[HID + j] + v1 * a2[HID + j + HQ] +
          v2 * a2[HID + j + 2 * HQ] + v3 * a2[HID + j + 3 * HQ];
  }
  __shared__ float2 rb[256];
  rb[t] = make_float2(s0, s1);
  __syncthreads();
  for (int s = 128; s > 0; s >>= 1) {
    if (t < s) { rb[t].x += rb[t + s].x; rb[t].y += rb[t + s].y; }
    __syncthreads();
  }
  if (t == 0) { ws[T2_OFF + b * 2] = rb[0].x; ws[T2_OFF + b * 2 + 1] = rb[0].y; }
}

// ---------------------------------------------------------------------------
// down: 256 blocks x 512 thr (8 waves). hs bf16 staged once in 88KB LDS.
// Cols: cA = blockIdx*8+wave, cB = cA+2048. WB's loads pinned before compute.
#define DN_LOADW(OCOL, W) do {                                              \
    const float4* _wp = (const float4*)w2q + (size_t)(OCOL) * 688;          \
    _Pragma("unroll")                                                       \
    for (int cc = 0; cc < 10; ++cc) {                                       \
      const float4 wv = _wp[cc * 64 + lane];                                \
      W[cc][0] = wv.x; W[cc][1] = wv.y; W[cc][2] = wv.z; W[cc][3] = wv.w;   \
    }                                                                       \
    {                                                                       \
      const float4 wv = _wp[640 + (lane < 48 ? lane : 0)];                  \
      W[10][0] = wv.x; W[10][1] = wv.y; W[10][2] = wv.z; W[10][3] = wv.w;   \
    }                                                                       \
  } while (0)

#define DN_COMPUTE(OCOL, W) do {                                            \
    float V[16];                                                            \
    _Pragma("unroll") for (int i = 0; i < 16; ++i) V[i] = 0.f;              \
    _Pragma("unroll")                                                       \
    for (int cc = 0; cc < 10; ++cc) {                                       \
      const int j = cc * 64 + lane;                                         \
      _Pragma("unroll")                                                     \
      for (int b = 0; b < 16; ++b) {                                        \
        uint2 p = ldsb[b * 688 + j];                                        \
        float x0 = __uint_as_float(p.x << 16);                              \
        float x1 = __uint_as_float(p.x & 0xffff0000u);                      \
        float x2 = __uint_as_float(p.y << 16);                              \
        float x3 = __uint_as_float(p.y & 0xffff0000u);                      \
        V[b] += W[cc][0] * x0 + W[cc][1] * x1 + W[cc][2] * x2 + W[cc][3] * x3; \
      }                                                                     \
    }                                                                       \
    if (lane < 48) {                                                        \
      const int j = 640 + lane;                                             \
      _Pragma("unroll")                                                     \
      for (int b = 0; b < 16; ++b) {                                        \
        uint2 p = ldsb[b * 688 + j];                                        \
        float x0 = __uint_as_float(p.x << 16);                              \
        float x1 = __uint_as_float(p.x & 0xffff0000u);                      \
        float x2 = __uint_as_float(p.y << 16);                              \
        float x3 = __uint_as_float(p.y & 0xffff0000u);                      \
        V[b] += W[10][0] * x0 + W[10][1] * x1 + W[10][2] * x2 + W[10][3] * x3; \
      }                                                                     \
    }                                                                       \
    _Pragma("unroll")                                                       \
    for (int s = 0; s < 4; ++s) {                                           \
      const int off = 1 << s, n2 = 8 >> s;                                  \
      _Pragma("unroll")                                                     \
      for (int i = 0; i < n2; ++i) {                                        \
        float lo = V[i], hi = V[i + n2];                                    \
        float send = (lane & off) ? lo : hi;                                \
        float got = __shfl_xor(send, off);                                  \
        V[i] = (lane & off) ? (hi + got) : (lo + got);                      \
      }                                                                     \
    }                                                                       \
    V[0] += __shfl_xor(V[0], 16);                                           \
    V[0] += __shfl_xor(V[0], 32);                                           \
    if (lane < 16) {                                                        \
      const int b = ((lane & 1) << 3) | ((lane & 2) << 1) |                 \
                    ((lane & 4) >> 1) | ((lane & 8) >> 3);                  \
      out[b * DMODEL + (OCOL)] = V[0] +                                     \
          0.5f * (ws[T2_OFF + 2 * b] * b2[2 * (OCOL)] +                     \
                  ws[T2_OFF + 2 * b + 1] * b2[2 * (OCOL) + 1]);             \
    }                                                                       \
  } while (0)

__global__ __launch_bounds__(512) void k_down(const float* __restrict__ w2q,
                                              const float* __restrict__ b2,
                                              const float* __restrict__ ws,
                                              float* __restrict__ out) {
  __shared__ uint4 lds4[5504];   // hs bf16 [16][2752] = 88 KB
  const int t = threadIdx.x;
  const int wave = t >> 6, lane = t & 63;
  const int cA = blockIdx.x * 8 + wave;        // 0..2047
  const int cB = cA + 2048;                    // 2048..4095

  float WA[11][4], WB[11][4];
  DN_LOADW(cA, WA);              // in flight during staging

  const uint4* hsb4 = (const uint4*)(ws + HSB_OFF);
#pragma unroll
  for (int i = 0; i < 10; ++i) lds4[t + i * 512] = hsb4[t + i * 512];
  if (t < 384) lds4[5120 + t] = hsb4[5120 + t];
  __syncthreads();

  const uint2* ldsb = (const uint2*)lds4;      // [b*688 + j], 4 bf16 each
  DN_LOADW(cB, WB);              // pinned in flight across compute A
  __builtin_amdgcn_sched_barrier(0);
  DN_COMPUTE(cA, WA);
  DN_COMPUTE(cB, WB);
}

// ---------------------------------------------------------------------------
extern "C" void kernel_launch(void* const* d_in, const int* in_sizes, int n_in,
                              void* d_out, int out_size, void* d_ws, size_t ws_size,
                              hipStream_t stream) {
  const float* x   = (const float*)d_in[0];
  const float* w1q = (const float*)d_in[1];
  const float* a1  = (const float*)d_in[2];
  const float* b1  = (const float*)d_in[3];
  const float* w3q = (const float*)d_in[4];
  const float* a3  = (const float*)d_in[5];
  const float* b3  = (const float*)d_in[6];
  const float* w2q = (const float*)d_in[7];
  const float* a2  = (const float*)d_in[8];
  const float* b2  = (const float*)d_in[9];
  float* out = (float*)d_out;
  float* ws  = (float*)d_ws;
  float* hvecT = ws + HVT_OFF;

  k_prep1<<<16, 256, 0, stream>>>(x, a1, a3, ws);
  k_gateup<<<512, 512, 0, stream>>>(w1q, w3q, b1, b3, ws, hvecT);
  k_prep2<<<16, 256, 0, stream>>>(hvecT, a2, ws);
  k_down<<<256, 512, 0, stream>>>(w2q, b2, ws, out);
}

// Round 8
// 48.868 us; speedup vs baseline: 1.6419x; 1.6419x over previous
//
#include <hip/hip_runtime.h>
#include <hip/hip_bf16.h>

// QLoRA SwiGLU MLP, B=16 tokens, d=4096, h=11008, r=2.
// tile(wq,(1,4)) => x @ W^T == fold4(x) @ wq^T  (skinny GEMM, K = in/4).
// R8: MFMA redesign. Scalar-FMA path failed 3x on the same constraint:
// 512-thr blocks cap VGPR at 128 < weights-in-flight needed (R2/R5/R7 spills).
// Now: 256-thr/4-wave blocks (VGPR cap 256), mfma_f32_16x16x32_bf16,
// weights f32->bf16 converted in-register, activations bf16 read straight
// from ws (L2-resident, 32/44 KB) as B-fragments. No LDS staging, no
// shuffle reduce; K-split across the 4 waves, 4-8KB LDS reduce, epilogue
// (LoRA r=2 + silu) fused in wave 0.
// Fragment maps (guide-verified): A/B: own-idx = lane&15, k = (lane>>4)*8+j
// (8 contiguous k elems); C/D: col(n) = lane&15, row(m) = (lane>>4)*4+reg.

#define NB     16
#define DMODEL 4096
#define HID    11008
#define DQ     1024   // DMODEL/4
#define HQ     2752   // HID/4

// workspace layout (float offsets)
#define XSB_OFF 0         // xs bf16 [16][1024] = 8192 floats
#define T1_OFF  8192      // [16][2] f32
#define T3_OFF  8224
#define HVT_OFF 8256      // hvecT f32 [11008][16]
#define HSB_OFF 184384    // hs bf16 [16][2752] = 22016 floats
#define T2_OFF  206400    // [16][2] f32

typedef __attribute__((ext_vector_type(8))) short bf16x8;
typedef __attribute__((ext_vector_type(4))) float f32x4;

__device__ __forceinline__ unsigned short f2bf(float f) {
  unsigned u = __float_as_uint(f);
  unsigned r = u + 0x7fffu + ((u >> 16) & 1u);   // RNE
  return (unsigned short)(r >> 16);
}
__device__ __forceinline__ unsigned pack2(float lo, float hi) {
  return (unsigned)f2bf(lo) | ((unsigned)f2bf(hi) << 16);
}
__device__ __forceinline__ bf16x8 cvt8(const float4 a, const float4 b) {
  uint4 u = make_uint4(pack2(a.x, a.y), pack2(a.z, a.w),
                       pack2(b.x, b.y), pack2(b.z, b.w));
  return __builtin_bit_cast(bf16x8, u);
}

// ---------------------------------------------------------------------------
// prep1: xs[b][j] = sum_k x[b][k*1024+j] stored bf16; t1,t3 = LoRA A dots.
__global__ __launch_bounds__(256) void k_prep1(const float* __restrict__ x,
                                               const float* __restrict__ a1,
                                               const float* __restrict__ a3,
                                               float* __restrict__ ws) {
  const int b = blockIdx.x, t = threadIdx.x;
  const float4* x4  = (const float4*)(x) + b * (DMODEL / 4);
  const float4* a14 = (const float4*)a1;
  const float4* a34 = (const float4*)a3;
  float4 xs = make_float4(0.f, 0.f, 0.f, 0.f);
  float s10 = 0.f, s11 = 0.f, s30 = 0.f, s31 = 0.f;
#pragma unroll
  for (int k = 0; k < 4; ++k) {
    float4 xv  = x4[k * 256 + t];
    xs.x += xv.x; xs.y += xv.y; xs.z += xv.z; xs.w += xv.w;
    float4 a10 = a14[k * 256 + t];
    float4 a11 = a14[1024 + k * 256 + t];
    float4 a30 = a34[k * 256 + t];
    float4 a31 = a34[1024 + k * 256 + t];
    s10 += xv.x * a10.x + xv.y * a10.y + xv.z * a10.z + xv.w * a10.w;
    s11 += xv.x * a11.x + xv.y * a11.y + xv.z * a11.z + xv.w * a11.w;
    s30 += xv.x * a30.x + xv.y * a30.y + xv.z * a30.z + xv.w * a30.w;
    s31 += xv.x * a31.x + xv.y * a31.y + xv.z * a31.z + xv.w * a31.w;
  }
  ((uint2*)(ws + XSB_OFF))[b * 256 + t] =
      make_uint2(pack2(xs.x, xs.y), pack2(xs.z, xs.w));

  __shared__ float4 rb[256];
  rb[t] = make_float4(s10, s11, s30, s31);
  __syncthreads();
  for (int s = 128; s > 0; s >>= 1) {
    if (t < s) {
      rb[t].x += rb[t + s].x; rb[t].y += rb[t + s].y;
      rb[t].z += rb[t + s].z; rb[t].w += rb[t + s].w;
    }
    __syncthreads();
  }
  if (t == 0) {
    ws[T1_OFF + b * 2]     = rb[0].x;
    ws[T1_OFF + b * 2 + 1] = rb[0].y;
    ws[T3_OFF + b * 2]     = rb[0].z;
    ws[T3_OFF + b * 2 + 1] = rb[0].w;
  }
}

// ---------------------------------------------------------------------------
// gateup: 688 blocks x 256 thr (4 waves). Tile = 16 out cols; wave w owns
// K-chunk [w*256, w*256+256). Per kk: 4 f32x4 weight loads + cvt + shared
// bf16 B-frag from global xs + 2 MFMA. LDS reduce, epilogue in wave 0.
__global__ __launch_bounds__(256) void k_gateup(const float* __restrict__ w1q,
                                                const float* __restrict__ w3q,
                                                const float* __restrict__ b1,
                                                const float* __restrict__ b3,
                                                const float* __restrict__ ws,
                                                float* __restrict__ hvecT) {
  __shared__ float red[4][8][64];
  const int t = threadIdx.x, w = t >> 6, l = t & 63;
  const int tile = blockIdx.x;
  const int n  = l & 15;            // A row / B col selector for this lane
  const int kb = (l >> 4) * 8;      // k sub-offset within each 32-block
  const int o  = tile * 16 + n;     // weight row this lane loads
  const unsigned short* xsb = (const unsigned short*)(ws + XSB_OFF);

  f32x4 acc1 = {0.f, 0.f, 0.f, 0.f}, acc3 = {0.f, 0.f, 0.f, 0.f};
  const int k0 = w * 256;
#pragma unroll
  for (int kk = 0; kk < 8; ++kk) {
    const int kabs = k0 + kk * 32 + kb;
    const float4* p1 = (const float4*)(w1q + (size_t)o * DQ + kabs);
    const float4* p3 = (const float4*)(w3q + (size_t)o * DQ + kabs);
    const bf16x8 bb = *(const bf16x8*)(xsb + n * DQ + kabs);
    const bf16x8 a1f = cvt8(p1[0], p1[1]);
    const bf16x8 a3f = cvt8(p3[0], p3[1]);
    acc1 = __builtin_amdgcn_mfma_f32_16x16x32_bf16(a1f, bb, acc1, 0, 0, 0);
    acc3 = __builtin_amdgcn_mfma_f32_16x16x32_bf16(a3f, bb, acc3, 0, 0, 0);
  }
#pragma unroll
  for (int r = 0; r < 4; ++r) {
    red[w][r][l]     = acc1[r];
    red[w][r + 4][l] = acc3[r];
  }
  __syncthreads();
  if (w == 0) {
    const float t10 = ws[T1_OFF + 2 * n], t11 = ws[T1_OFF + 2 * n + 1];
    const float t30 = ws[T3_OFF + 2 * n], t31 = ws[T3_OFF + 2 * n + 1];
    const int m4 = (l >> 4) * 4;
#pragma unroll
    for (int r = 0; r < 4; ++r) {
      const float g0 = red[0][r][l] + red[1][r][l] + red[2][r][l] + red[3][r][l];
      const float u0 = red[0][r + 4][l] + red[1][r + 4][l] +
                       red[2][r + 4][l] + red[3][r + 4][l];
      const int oo = tile * 16 + m4 + r;
      const float g = g0 + 0.5f * (t10 * b1[2 * oo] + t11 * b1[2 * oo + 1]);
      const float u = u0 + 0.5f * (t30 * b3[2 * oo] + t31 * b3[2 * oo + 1]);
      hvecT[oo * 16 + n] = (g / (1.f + __expf(-g))) * u;
    }
  }
}

// ---------------------------------------------------------------------------
// prep2: hs[b][j] = sum_k hvec[b][k*2752+j] (stored bf16); t2 = hvec·a2^T.
__global__ __launch_bounds__(256) void k_prep2(const float* __restrict__ hvecT,
                                               const float* __restrict__ a2,
                                               float* __restrict__ ws) {
  const int b = blockIdx.x, t = threadIdx.x;
  float s0 = 0.f, s1 = 0.f;
  unsigned short* hsb = (unsigned short*)(ws + HSB_OFF);
  for (int j = t; j < HQ; j += 256) {
    float v0 = hvecT[j * 16 + b];
    float v1 = hvecT[(j + HQ) * 16 + b];
    float v2 = hvecT[(j + 2 * HQ) * 16 + b];
    float v3 = hvecT[(j + 3 * HQ) * 16 + b];
    hsb[b * HQ + j] = f2bf(v0 + v1 + v2 + v3);
    s0 += v0 * a2[j] + v1 * a2[j + HQ] + v2 * a2[j + 2 * HQ] + v3 * a2[j + 3 * HQ];
    s1 += v0 * a2[HID + j] + v1 * a2[HID + j + HQ] +
          v2 * a2[HID + j + 2 * HQ] + v3 * a2[HID + j + 3 * HQ];
  }
  __shared__ float2 rb[256];
  rb[t] = make_float2(s0, s1);
  __syncthreads();
  for (int s = 128; s > 0; s >>= 1) {
    if (t < s) { rb[t].x += rb[t + s].x; rb[t].y += rb[t + s].y; }
    __syncthreads();
  }
  if (t == 0) { ws[T2_OFF + b * 2] = rb[0].x; ws[T2_OFF + b * 2 + 1] = rb[0].y; }
}

// ---------------------------------------------------------------------------
// down: 256 blocks x 256 thr (4 waves). Tile = 16 out cols; K=2752 split
// {22,22,21,21} kk-steps across waves. B-frags from global hs bf16.
__global__ __launch_bounds__(256) void k_down(const float* __restrict__ w2q,
                                              const float* __restrict__ b2,
                                              const float* __restrict__ ws,
                                              float* __restrict__ out) {
  __shared__ float red[4][4][64];
  const int t = threadIdx.x, w = t >> 6, l = t & 63;
  const int tile = blockIdx.x;
  const int n  = l & 15;
  const int kb = (l >> 4) * 8;
  const int o  = tile * 16 + n;
  const unsigned short* hsb = (const unsigned short*)(ws + HSB_OFF);

  f32x4 acc = {0.f, 0.f, 0.f, 0.f};
  const int kks  = (w < 2) ? w * 22 : 44 + (w - 2) * 21;
  const int klen = (w < 2) ? 22 : 21;
#pragma unroll
  for (int kk = 0; kk < 22; ++kk) {
    if (kk < klen) {                      // wave-uniform guard
      const int kabs = (kks + kk) * 32 + kb;
      const float4* p2 = (const float4*)(w2q + (size_t)o * HQ + kabs);
      const bf16x8 bb = *(const bf16x8*)(hsb + n * HQ + kabs);
      const bf16x8 af = cvt8(p2[0], p2[1]);
      acc = __builtin_amdgcn_mfma_f32_16x16x32_bf16(af, bb, acc, 0, 0, 0);
    }
  }
#pragma unroll
  for (int r = 0; r < 4; ++r) red[w][r][l] = acc[r];
  __syncthreads();
  if (w == 0) {
    const float t20 = ws[T2_OFF + 2 * n], t21 = ws[T2_OFF + 2 * n + 1];
    const int m4 = (l >> 4) * 4;
#pragma unroll
    for (int r = 0; r < 4; ++r) {
      const float v = red[0][r][l] + red[1][r][l] + red[2][r][l] + red[3][r][l];
      const int oo = tile * 16 + m4 + r;
      out[n * DMODEL + oo] = v + 0.5f * (t20 * b2[2 * oo] + t21 * b2[2 * oo + 1]);
    }
  }
}

// ---------------------------------------------------------------------------
extern "C" void kernel_launch(void* const* d_in, const int* in_sizes, int n_in,
                              void* d_out, int out_size, void* d_ws, size_t ws_size,
                              hipStream_t stream) {
  const float* x   = (const float*)d_in[0];
  const float* w1q = (const float*)d_in[1];
  const float* a1  = (const float*)d_in[2];
  const float* b1  = (const float*)d_in[3];
  const float* w3q = (const float*)d_in[4];
  const float* a3  = (const float*)d_in[5];
  const float* b3  = (const float*)d_in[6];
  const float* w2q = (const float*)d_in[7];
  const float* a2  = (const float*)d_in[8];
  const float* b2  = (const float*)d_in[9];
  float* out = (float*)d_out;
  float* ws  = (float*)d_ws;
  float* hvecT = ws + HVT_OFF;

  k_prep1<<<16, 256, 0, stream>>>(x, a1, a3, ws);
  k_gateup<<<HID / 16, 256, 0, stream>>>(w1q, w3q, b1, b3, ws, hvecT);
  k_prep2<<<16, 256, 0, stream>>>(hvecT, a2, ws);
  k_down<<<DMODEL / 16, 256, 0, stream>>>(w2q, b2, ws, out);
}